// Round 2
// 748.411 us; speedup vs baseline: 1.0566x; 1.0566x over previous
//
#include <hip/hip_runtime.h>

typedef unsigned int uint;
typedef unsigned short ushort_t;
typedef __attribute__((ext_vector_type(8))) short bf16x8_t;   // 8 bf16 (4 VGPRs)
typedef __attribute__((ext_vector_type(4))) float f32x4_t;    // MFMA acc

// Problem constants
constexpr int Bsz = 4096, NX = 64, NU = 16, NXU = 80, HID = 256, Hh = 50;
constexpr long NS = (long)Bsz * Hh * NU;   // noise per-iteration stride: 3,276,800
// Output offsets (floats), concatenated in return order
constexpr int O1 = 65536;                  // x_traj  (B,51,64)
constexpr int O2 = 13434880;               // pred    (B,50,64)
constexpr int O3 = 26542080;               // gx      (B,50,64)
constexpr int O4 = 39649280;               // gu      (B,50,16)
constexpr int XT_PITCH = (Hh + 1) * NX;    // 3264
constexpr int PR_PITCH = Hh * NX;          // 3200
constexpr int U_PITCH = Hh * NU;           // 800

// LDS strides (padded)
constexpr int W1S = 260;   // W1L row stride (floats)
constexpr int HS  = 264;   // hRT row stride (floats)
constexpr int TS  = 264;   // tT row stride (shorts)  (fallback kernel only)
constexpr int W2S = 264;   // W2T row stride (shorts)
constexpr int TLS = 264;   // K2 LDS row stride (shorts); 264*2=528 B, 16B-aligned

constexpr long T_BYTES = (long)Bsz * Hh * HID * 2;   // 104,857,600 B in d_ws

__device__ __forceinline__ float tanh_fast(float x) {
    float e = __expf(2.0f * x);
    return 1.0f - 2.0f / (e + 1.0f);   // safe at +/-inf
}
__device__ __forceinline__ uint f2bf_u(float x) {
    uint b = __float_as_uint(x);
    return (b + 0x7FFFu + ((b >> 16) & 1u)) >> 16;   // RNE, low 16 bits valid
}
__device__ __forceinline__ float bf2f(ushort_t u) {
    return __uint_as_float(((uint)u) << 16);
}
__device__ __forceinline__ void unpack8(uint4 v, float* f) {
    f[0] = __uint_as_float(v.x << 16); f[1] = __uint_as_float(v.x & 0xFFFF0000u);
    f[2] = __uint_as_float(v.y << 16); f[3] = __uint_as_float(v.y & 0xFFFF0000u);
    f[4] = __uint_as_float(v.z << 16); f[5] = __uint_as_float(v.z & 0xFFFF0000u);
    f[6] = __uint_as_float(v.w << 16); f[7] = __uint_as_float(v.w & 0xFFFF0000u);
}

// =====================================================================
// K1: sequential rollout (P1+P2), 16 batch rows/block, 256 blocks.
// Streams t = s*(1-h^2) (bf16) to d_ws for K2. No linearization here.
// (UNCHANGED from the 790 µs version.)
// =====================================================================
__global__ __launch_bounds__(256) void ker_roll(const float* __restrict__ x0,
                                                const float* __restrict__ W1,
                                                const float* __restrict__ b1,
                                                const float* __restrict__ W2,
                                                const float* __restrict__ noise,
                                                const int* __restrict__ nit_p,
                                                float* __restrict__ out,
                                                ushort_t* __restrict__ tg) {
    __shared__ __align__(16) float    W1L[NXU * W1S];   // 83,200 B
    __shared__ __align__(16) ushort_t W2T[NX * W2S];    // 33,792 B
    __shared__ __align__(16) float    hRT[16 * HS];     // 16,896 B
    __shared__ __align__(16) float    zT[NXU * 16];     //  5,120 B
    __shared__ float b1L[HID];                          //  1,024 B
    __shared__ float sL[HID];                           //  1,024 B
    // total 141,056 B

    const int tid = threadIdx.x;
    const int b0 = blockIdx.x * 16;
    const int nit = nit_p[0];

    for (int i = tid; i < NXU * HID; i += 256)
        W1L[(i >> 8) * W1S + (i & 255)] = W1[i];
    for (int i = tid; i < HID * NX; i += 256) {
        int c = i >> 6, d = i & 63;
        W2T[d * W2S + c] = (ushort_t)f2bf_u(W2[i]);
    }
    b1L[tid] = b1[tid];
    for (int i = tid; i < 16 * NX; i += 256) {
        int r = i >> 6, d = i & 63;
        float v = x0[(b0 + r) * NX + d];
        zT[d * 16 + r] = v;
        out[O1 + (b0 + r) * XT_PITCH + d] = v;
    }
    const int r16 = tid >> 4, q16 = tid & 15;
    {
        long base = (long)(b0 + r16) * U_PITCH + q16;
        float s = 0.f;
        for (int it = 0; it < nit - 1; ++it) s += noise[(long)it * NS + base];
        zT[(NX + q16) * 16 + r16] = 0.001f * s;
        out[(b0 + r16) * NU + q16] = 0.001f * (s + noise[(long)(nit - 1) * NS + base]);
    }
    __syncthreads();
    {
        float s = 0.f;
        for (int d = 0; d < NX; ++d) s += bf2f(W2T[d * W2S + tid]);
        sL[tid] = 0.1f * s;
    }

    const int ct = tid & 63, rt = tid >> 6;
    const uint* W2Tu = (const uint*)W2T;

    for (int k = 0; k < Hh; ++k) {
        __syncthreads();

        // prefetch next-step controls
        float v9[9];
        const bool fast = (k < Hh - 1) && (nit == 10);
        long nbase = (long)(b0 + r16) * U_PITCH + (k + 1) * NU + q16;
        if (fast) {
            #pragma unroll
            for (int it = 0; it < 9; ++it) v9[it] = noise[(long)it * NS + nbase];
        }

        // ---- P1: a = z@W1 + b1 ; h -> hRT ; t -> global (d_ws) ----
        float a_[4][4];
        {
            float bj[4];
            #pragma unroll
            for (int j = 0; j < 4; ++j) bj[j] = b1L[4 * ct + j];
            #pragma unroll
            for (int i = 0; i < 4; ++i)
                #pragma unroll
                for (int j = 0; j < 4; ++j) a_[i][j] = bj[j];
        }
        #pragma unroll 8
        for (int kk = 0; kk < NXU; ++kk) {
            float4 zv = *(const float4*)&zT[kk * 16 + 4 * rt];
            float4 wv = *(const float4*)&W1L[kk * W1S + 4 * ct];
            float zz[4] = {zv.x, zv.y, zv.z, zv.w};
            float ww[4] = {wv.x, wv.y, wv.z, wv.w};
            #pragma unroll
            for (int i = 0; i < 4; ++i)
                #pragma unroll
                for (int j = 0; j < 4; ++j) a_[i][j] += zz[i] * ww[j];
        }
        float h_[4][4];
        #pragma unroll
        for (int i = 0; i < 4; ++i)
            #pragma unroll
            for (int j = 0; j < 4; ++j) h_[i][j] = tanh_fast(a_[i][j]);
        #pragma unroll
        for (int i = 0; i < 4; ++i)
            *(float4*)&hRT[(4 * rt + i) * HS + 4 * ct] =
                make_float4(h_[i][0], h_[i][1], h_[i][2], h_[i][3]);
        {
            float s0 = sL[4 * ct], s1 = sL[4 * ct + 1], s2 = sL[4 * ct + 2], s3 = sL[4 * ct + 3];
            #pragma unroll
            for (int i = 0; i < 4; ++i) {
                float t0 = s0 * (1.f - h_[i][0] * h_[i][0]);
                float t1 = s1 * (1.f - h_[i][1] * h_[i][1]);
                float t2 = s2 * (1.f - h_[i][2] * h_[i][2]);
                float t3 = s3 * (1.f - h_[i][3] * h_[i][3]);
                size_t rho = (size_t)(b0 + 4 * rt + i) * Hh + k;
                uint2 pk = make_uint2(f2bf_u(t0) | (f2bf_u(t1) << 16),
                                      f2bf_u(t2) | (f2bf_u(t3) << 16));
                *(uint2*)(tg + rho * HID + 4 * ct) = pk;   // coalesced 512 B/row
            }
        }

        float unext = 0.f;
        if (k < Hh - 1) {
            if (fast) {
                #pragma unroll
                for (int it = 0; it < 9; ++it) unext += v9[it];
            } else {
                for (int it = 0; it < nit - 1; ++it) unext += noise[(long)it * NS + nbase];
            }
            unext *= 0.001f;
        }

        __syncthreads();

        // ---- P2: x_next = x + 0.1*h@W2 ----
        float xacc[4] = {0.f, 0.f, 0.f, 0.f};
        #pragma unroll 4
        for (int c8 = 0; c8 < HID / 8; ++c8) {
            float4 h0 = *(const float4*)&hRT[r16 * HS + 8 * c8];
            float4 h1 = *(const float4*)&hRT[r16 * HS + 8 * c8 + 4];
            float hf[8] = {h0.x, h0.y, h0.z, h0.w, h1.x, h1.y, h1.z, h1.w};
            #pragma unroll
            for (int i = 0; i < 4; ++i) {
                int d = q16 + 16 * i;
                uint4 wv = *(const uint4*)&W2Tu[d * (W2S / 2) + 4 * c8];
                float wf[8];
                unpack8(wv, wf);
                #pragma unroll
                for (int jj = 0; jj < 8; ++jj) xacc[i] += hf[jj] * wf[jj];
            }
        }
        {
            const int bb = b0 + r16;
            #pragma unroll
            for (int i = 0; i < 4; ++i) {
                int d = q16 + 16 * i;
                float xn = zT[d * 16 + r16] + 0.1f * xacc[i];
                out[O1 + bb * XT_PITCH + (k + 1) * NX + d] = xn;
                out[O2 + bb * PR_PITCH + k * NX + d] = xn;
                zT[d * 16 + r16] = xn;
            }
            if (k < Hh - 1) zT[(NX + q16) * 16 + r16] = unext;
        }
    }
}

// =====================================================================
// K2 (rewritten): G[204800 x 80] = T[204800 x 256] @ W1^T, bf16 MFMA.
// - NO T staging in LDS: A-fragments load directly from global (each T
//   row is consumed by exactly one wave; LDS round trip was pure cost).
// - Only W1-bf16 kept in LDS (42 KB -> 3 blocks/CU vs 1 before),
//   staged with vectorized float4 loads + packed converts.
// - No barrier in the main loop; compiler can hoist all 16 global
//   A-loads of the k-sweep ahead of the MFMAs.
// gx = 1 + G[:, :64], gu = G[:, 64:80]. 1600 blocks x 128 rows.
// =====================================================================
__global__ __launch_bounds__(256) void ker_lin2(const float* __restrict__ W1,
                                                const ushort_t* __restrict__ Tg,
                                                float* __restrict__ out) {
    __shared__ __align__(16) ushort_t W1b[NXU * TLS];   // 42,240 B (only LDS)

    const int tid = threadIdx.x;
    const int r0 = blockIdx.x * 128;

    // Stage W1 (f32, L2-resident) -> bf16 LDS. 5120 float4 = 20/thread.
    {
        const float4* W1f4 = (const float4*)W1;
        for (int i = tid; i < (NXU * HID) / 4; i += 256) {
            float4 w = W1f4[i];
            int p = i >> 6, c4 = i & 63;   // row p, cols 4*c4..4*c4+3
            uint2 pk = make_uint2(f2bf_u(w.x) | (f2bf_u(w.y) << 16),
                                  f2bf_u(w.z) | (f2bf_u(w.w) << 16));
            *(uint2*)&W1b[p * TLS + 4 * c4] = pk;   // 528*p + 8*c4 bytes: 8B-aligned
        }
    }
    __syncthreads();

    const int wv = tid >> 6, lane = tid & 63;
    const int m = lane & 15, quad = lane >> 4;

    f32x4_t acc[2][5];
    #pragma unroll
    for (int i = 0; i < 2; ++i)
        #pragma unroll
        for (int j = 0; j < 5; ++j) acc[i][j] = (f32x4_t){0.f, 0.f, 0.f, 0.f};

    // A-fragment rows for this lane: global T rows (r0 + wv*32 + m) and (+16)
    const ushort_t* Ta = Tg + (size_t)(r0 + wv * 32 + m) * HID;
    const ushort_t* Tb = Ta + (size_t)16 * HID;

    #pragma unroll
    for (int kc = 0; kc < 8; ++kc) {
        const int koff = kc * 32 + quad * 8;               // bytes: 64*kc+16*quad (16B-aligned)
        bf16x8_t a0 = *(const bf16x8_t*)&Ta[koff];
        bf16x8_t a1 = *(const bf16x8_t*)&Tb[koff];
        #pragma unroll
        for (int nt = 0; nt < 5; ++nt) {
            bf16x8_t bfr = *(const bf16x8_t*)&W1b[(nt * 16 + m) * TLS + koff];
            acc[0][nt] = __builtin_amdgcn_mfma_f32_16x16x32_bf16(a0, bfr, acc[0][nt], 0, 0, 0);
            acc[1][nt] = __builtin_amdgcn_mfma_f32_16x16x32_bf16(a1, bfr, acc[1][nt], 0, 0, 0);
        }
    }

    // Epilogue: C/D layout col=lane&15, row=quad*4+reg  (unchanged, verified)
    #pragma unroll
    for (int mt = 0; mt < 2; ++mt) {
        int rbase = r0 + wv * 32 + mt * 16 + quad * 4;
        #pragma unroll
        for (int r = 0; r < 4; ++r) {
            int rho = rbase + r;
            int b = (int)(((unsigned long long)rho * 1374389535ULL) >> 36);  // rho/50
            int kk = rho - b * 50;
            float* gxp = out + O3 + (size_t)b * PR_PITCH + kk * NX + m;
            #pragma unroll
            for (int nt = 0; nt < 4; ++nt)
                gxp[nt * 16] = 1.0f + acc[mt][nt][r];
            out[O4 + (size_t)b * U_PITCH + kk * NU + m] = acc[mt][4][r];
        }
    }
}

// =====================================================================
// Fallback: R2's proven fused kernel (used only if ws_size is too small)
// =====================================================================
__global__ __launch_bounds__(256) void ker_fused(const float* __restrict__ x0,
                                                 const float* __restrict__ W1,
                                                 const float* __restrict__ b1,
                                                 const float* __restrict__ W2,
                                                 const float* __restrict__ noise,
                                                 const int* __restrict__ nit_p,
                                                 float* __restrict__ out) {
    __shared__ __align__(16) float    W1L[NXU * W1S];
    __shared__ __align__(16) ushort_t W2T[NX * W2S];
    __shared__ __align__(16) float    hRT[16 * HS];
    __shared__ __align__(16) ushort_t tT[16 * TS];
    __shared__ __align__(16) float    zT[NXU * 16];
    __shared__ float b1L[HID];
    __shared__ float sL[HID];

    const int tid = threadIdx.x;
    const int b0 = blockIdx.x * 16;
    const int nit = nit_p[0];

    for (int i = tid; i < NXU * HID; i += 256)
        W1L[(i >> 8) * W1S + (i & 255)] = W1[i];
    for (int i = tid; i < HID * NX; i += 256) {
        int c = i >> 6, d = i & 63;
        W2T[d * W2S + c] = (ushort_t)f2bf_u(W2[i]);
    }
    b1L[tid] = b1[tid];
    for (int i = tid; i < 16 * NX; i += 256) {
        int r = i >> 6, d = i & 63;
        float v = x0[(b0 + r) * NX + d];
        zT[d * 16 + r] = v;
        out[O1 + (b0 + r) * XT_PITCH + d] = v;
    }
    const int r16 = tid >> 4, q16 = tid & 15;
    {
        long base = (long)(b0 + r16) * U_PITCH + q16;
        float s = 0.f;
        for (int it = 0; it < nit - 1; ++it) s += noise[(long)it * NS + base];
        zT[(NX + q16) * 16 + r16] = 0.001f * s;
        out[(b0 + r16) * NU + q16] = 0.001f * (s + noise[(long)(nit - 1) * NS + base]);
    }
    __syncthreads();
    {
        float s = 0.f;
        for (int d = 0; d < NX; ++d) s += bf2f(W2T[d * W2S + tid]);
        sL[tid] = 0.1f * s;
    }

    const int ct = tid & 63, rt = tid >> 6;
    uint* tTu = (uint*)tT;
    const uint* W2Tu = (const uint*)W2T;

    for (int k = 0; k < Hh; ++k) {
        __syncthreads();
        float v9[9];
        const bool fast = (k < Hh - 1) && (nit == 10);
        long nbase = (long)(b0 + r16) * U_PITCH + (k + 1) * NU + q16;
        if (fast) {
            #pragma unroll
            for (int it = 0; it < 9; ++it) v9[it] = noise[(long)it * NS + nbase];
        }
        float a_[4][4];
        {
            float bj[4];
            #pragma unroll
            for (int j = 0; j < 4; ++j) bj[j] = b1L[4 * ct + j];
            #pragma unroll
            for (int i = 0; i < 4; ++i)
                #pragma unroll
                for (int j = 0; j < 4; ++j) a_[i][j] = bj[j];
        }
        #pragma unroll 8
        for (int kk = 0; kk < NXU; ++kk) {
            float4 zv = *(const float4*)&zT[kk * 16 + 4 * rt];
            float4 wv = *(const float4*)&W1L[kk * W1S + 4 * ct];
            float zz[4] = {zv.x, zv.y, zv.z, zv.w};
            float ww[4] = {wv.x, wv.y, wv.z, wv.w};
            #pragma unroll
            for (int i = 0; i < 4; ++i)
                #pragma unroll
                for (int j = 0; j < 4; ++j) a_[i][j] += zz[i] * ww[j];
        }
        float h_[4][4];
        #pragma unroll
        for (int i = 0; i < 4; ++i)
            #pragma unroll
            for (int j = 0; j < 4; ++j) h_[i][j] = tanh_fast(a_[i][j]);
        #pragma unroll
        for (int i = 0; i < 4; ++i)
            *(float4*)&hRT[(4 * rt + i) * HS + 4 * ct] =
                make_float4(h_[i][0], h_[i][1], h_[i][2], h_[i][3]);
        {
            float s0 = sL[4 * ct], s1 = sL[4 * ct + 1], s2 = sL[4 * ct + 2], s3 = sL[4 * ct + 3];
            #pragma unroll
            for (int i = 0; i < 4; ++i) {
                float t0 = s0 * (1.f - h_[i][0] * h_[i][0]);
                float t1 = s1 * (1.f - h_[i][1] * h_[i][1]);
                float t2 = s2 * (1.f - h_[i][2] * h_[i][2]);
                float t3 = s3 * (1.f - h_[i][3] * h_[i][3]);
                tTu[(4 * rt + i) * (TS / 2) + 2 * ct]     = f2bf_u(t0) | (f2bf_u(t1) << 16);
                tTu[(4 * rt + i) * (TS / 2) + 2 * ct + 1] = f2bf_u(t2) | (f2bf_u(t3) << 16);
            }
        }
        float unext = 0.f;
        if (k < Hh - 1) {
            if (fast) {
                #pragma unroll
                for (int it = 0; it < 9; ++it) unext += v9[it];
            } else {
                for (int it = 0; it < nit - 1; ++it) unext += noise[(long)it * NS + nbase];
            }
            unext *= 0.001f;
        }
        __syncthreads();
        float xacc[4] = {0.f, 0.f, 0.f, 0.f};
        #pragma unroll 4
        for (int c8 = 0; c8 < HID / 8; ++c8) {
            float4 h0 = *(const float4*)&hRT[r16 * HS + 8 * c8];
            float4 h1 = *(const float4*)&hRT[r16 * HS + 8 * c8 + 4];
            float hf[8] = {h0.x, h0.y, h0.z, h0.w, h1.x, h1.y, h1.z, h1.w};
            #pragma unroll
            for (int i = 0; i < 4; ++i) {
                int d = q16 + 16 * i;
                uint4 wv = *(const uint4*)&W2Tu[d * (W2S / 2) + 4 * c8];
                float wf[8];
                unpack8(wv, wf);
                #pragma unroll
                for (int jj = 0; jj < 8; ++jj) xacc[i] += hf[jj] * wf[jj];
            }
        }
        {
            const int bb = b0 + r16;
            #pragma unroll
            for (int i = 0; i < 4; ++i) {
                int d = q16 + 16 * i;
                float xn = zT[d * 16 + r16] + 0.1f * xacc[i];
                out[O1 + bb * XT_PITCH + (k + 1) * NX + d] = xn;
                out[O2 + bb * PR_PITCH + k * NX + d] = xn;
                zT[d * 16 + r16] = xn;
            }
            if (k < Hh - 1) zT[(NX + q16) * 16 + r16] = unext;
        }
        {
            const uint* tTr = (const uint*)tT + r16 * (TS / 2);
            float g_[5] = {0.f, 0.f, 0.f, 0.f, 0.f};
            #pragma unroll 4
            for (int jc = 0; jc < HID / 8; ++jc) {
                uint4 tv = *(const uint4*)&tTr[4 * jc];
                float tf[8];
                unpack8(tv, tf);
                #pragma unroll
                for (int i = 0; i < 5; ++i) {
                    int p = q16 + 16 * i;
                    float4 w0 = *(const float4*)&W1L[p * W1S + 8 * jc];
                    float4 w1 = *(const float4*)&W1L[p * W1S + 8 * jc + 4];
                    g_[i] += tf[0] * w0.x + tf[1] * w0.y + tf[2] * w0.z + tf[3] * w0.w
                           + tf[4] * w1.x + tf[5] * w1.y + tf[6] * w1.z + tf[7] * w1.w;
                }
            }
            const int bb = b0 + r16;
            #pragma unroll
            for (int i = 0; i < 4; ++i)
                out[O3 + bb * PR_PITCH + k * NX + (q16 + 16 * i)] = 1.0f + g_[i];
            out[O4 + bb * U_PITCH + k * NU + q16] = g_[4];
        }
    }
}

extern "C" void kernel_launch(void* const* d_in, const int* in_sizes, int n_in,
                              void* d_out, int out_size, void* d_ws, size_t ws_size,
                              hipStream_t stream) {
    const float* x0    = (const float*)d_in[0];
    // d_in[1] = xref (unused)
    const float* W1    = (const float*)d_in[2];
    const float* b1    = (const float*)d_in[3];
    const float* W2    = (const float*)d_in[4];
    const float* noise = (const float*)d_in[5];
    const int*   nit   = (const int*)d_in[6];
    float* out = (float*)d_out;

    if (ws_size >= (size_t)T_BYTES) {
        ushort_t* tg = (ushort_t*)d_ws;
        ker_roll<<<Bsz / 16, 256, 0, stream>>>(x0, W1, b1, W2, noise, nit, out, tg);
        ker_lin2<<<(Bsz * Hh) / 128, 256, 0, stream>>>(W1, tg, out);
    } else {
        ker_fused<<<Bsz / 16, 256, 0, stream>>>(x0, W1, b1, W2, noise, nit, out);
    }
}

// Round 3
// 730.556 us; speedup vs baseline: 1.0824x; 1.0244x over previous
//
#include <hip/hip_runtime.h>

typedef unsigned int uint;
typedef unsigned short ushort_t;
typedef __attribute__((ext_vector_type(8))) short bf16x8_t;   // 8 bf16 (4 VGPRs)
typedef __attribute__((ext_vector_type(4))) float f32x4_t;    // MFMA acc

// Problem constants
constexpr int Bsz = 4096, NX = 64, NU = 16, NXU = 80, HID = 256, Hh = 50;
constexpr long NS = (long)Bsz * Hh * NU;   // noise per-iteration stride: 3,276,800
// Output offsets (floats), concatenated in return order
constexpr int O1 = 65536;                  // x_traj  (B,51,64)
constexpr int O2 = 13434880;               // pred    (B,50,64)
constexpr int O3 = 26542080;               // gx      (B,50,64)
constexpr int O4 = 39649280;               // gu      (B,50,16)
constexpr int XT_PITCH = (Hh + 1) * NX;    // 3264
constexpr int PR_PITCH = Hh * NX;          // 3200
constexpr int U_PITCH = Hh * NU;           // 800

// LDS strides (padded)
constexpr int W1S = 260;   // W1L row stride (floats)
constexpr int HS  = 264;   // hRT row stride (floats)  (fallback kernel)
constexpr int HSR = 260;   // hRT row stride (floats)  (ker_roll: 16 distinct rows read -> 2-way)
constexpr int TS  = 264;   // tT row stride (shorts)   (fallback kernel only)
constexpr int W2S = 264;   // W2T row stride (shorts)
constexpr int TLS = 264;   // K2 LDS row stride (shorts); 264*2=528 B, 16B-aligned

constexpr long T_BYTES = (long)Bsz * Hh * HID * 2;   // 104,857,600 B in d_ws

__device__ __forceinline__ float tanh_fast(float x) {
    float e = __expf(2.0f * x);
    return 1.0f - 2.0f / (e + 1.0f);   // safe at +/-inf
}
__device__ __forceinline__ uint f2bf_u(float x) {
    uint b = __float_as_uint(x);
    return (b + 0x7FFFu + ((b >> 16) & 1u)) >> 16;   // RNE, low 16 bits valid
}
__device__ __forceinline__ float bf2f(ushort_t u) {
    return __uint_as_float(((uint)u) << 16);
}
__device__ __forceinline__ void unpack8(uint4 v, float* f) {
    f[0] = __uint_as_float(v.x << 16); f[1] = __uint_as_float(v.x & 0xFFFF0000u);
    f[2] = __uint_as_float(v.y << 16); f[3] = __uint_as_float(v.y & 0xFFFF0000u);
    f[4] = __uint_as_float(v.z << 16); f[5] = __uint_as_float(v.z & 0xFFFF0000u);
    f[6] = __uint_as_float(v.w << 16); f[7] = __uint_as_float(v.w & 0xFFFF0000u);
}

// =====================================================================
// K1: sequential rollout (P1+P2), 16 batch rows/block, 256 blocks.
// NOW 512 threads/block (2 waves/SIMD instead of 1) — same math, same
// accumulation order per output (bitwise-identical results); only the
// thread->work mapping changed. Streams t (bf16) to d_ws for K2.
// =====================================================================
__global__ __launch_bounds__(512, 2) void ker_roll(const float* __restrict__ x0,
                                                   const float* __restrict__ W1,
                                                   const float* __restrict__ b1,
                                                   const float* __restrict__ W2,
                                                   const float* __restrict__ noise,
                                                   const int* __restrict__ nit_p,
                                                   float* __restrict__ out,
                                                   ushort_t* __restrict__ tg) {
    __shared__ __align__(16) float    W1L[NXU * W1S];   // 83,200 B
    __shared__ __align__(16) ushort_t W2T[NX * W2S];    // 33,792 B
    __shared__ __align__(16) float    hRT[16 * HSR];    // 16,640 B
    __shared__ __align__(16) float    zT[NXU * 16];     //  5,120 B
    __shared__ float b1L[HID];                          //  1,024 B
    __shared__ float sL[HID];                           //  1,024 B
    // total 140,800 B -> 1 block (8 waves) / CU

    const int tid = threadIdx.x;
    const int b0 = blockIdx.x * 16;
    const int nit = nit_p[0];

    for (int i = tid; i < NXU * HID; i += 512)
        W1L[(i >> 8) * W1S + (i & 255)] = W1[i];
    for (int i = tid; i < HID * NX; i += 512) {
        int c = i >> 6, d = i & 63;
        W2T[d * W2S + c] = (ushort_t)f2bf_u(W2[i]);
    }
    if (tid < HID) b1L[tid] = b1[tid];
    for (int i = tid; i < 16 * NX; i += 512) {
        int r = i >> 6, d = i & 63;
        float v = x0[(b0 + r) * NX + d];
        zT[d * 16 + r] = v;
        out[O1 + (b0 + r) * XT_PITCH + d] = v;
    }
    const int r16n = (tid >> 4) & 15, q16n = tid & 15;   // noise/control mapping (tid<256)
    if (tid < 256) {
        long base = (long)(b0 + r16n) * U_PITCH + q16n;
        float s = 0.f;
        for (int it = 0; it < nit - 1; ++it) s += noise[(long)it * NS + base];
        zT[(NX + q16n) * 16 + r16n] = 0.001f * s;
        out[(b0 + r16n) * NU + q16n] = 0.001f * (s + noise[(long)(nit - 1) * NS + base]);
    }
    __syncthreads();
    if (tid < HID) {
        float s = 0.f;
        for (int d = 0; d < NX; ++d) s += bf2f(W2T[d * W2S + tid]);
        sL[tid] = 0.1f * s;
    }

    const int ct = tid & 63, rt8 = tid >> 6;   // P1: rows {2*rt8, 2*rt8+1} (wave-uniform), cols 4*ct..
    const int q16 = tid & 15, cg = tid >> 4;   // P2: row q16, cols {cg, cg+32}
    const uint* W2Tu = (const uint*)W2T;

    for (int k = 0; k < Hh; ++k) {
        __syncthreads();

        // prefetch next-step controls (tid<256 handles the 16x16 control tile)
        float v9[9];
        const bool fast = (k < Hh - 1) && (nit == 10);
        long nbase = (long)(b0 + r16n) * U_PITCH + (k + 1) * NU + q16n;
        if (fast && tid < 256) {
            #pragma unroll
            for (int it = 0; it < 9; ++it) v9[it] = noise[(long)it * NS + nbase];
        }

        // ---- P1: a = z@W1 + b1 ; h -> hRT ; t -> global (d_ws) ----
        float a_[2][4];
        {
            float bj[4];
            #pragma unroll
            for (int j = 0; j < 4; ++j) bj[j] = b1L[4 * ct + j];
            #pragma unroll
            for (int i = 0; i < 2; ++i)
                #pragma unroll
                for (int j = 0; j < 4; ++j) a_[i][j] = bj[j];
        }
        #pragma unroll 8
        for (int kk = 0; kk < NXU; ++kk) {
            float2 zv = *(const float2*)&zT[kk * 16 + 2 * rt8];   // wave-uniform broadcast
            float4 wv = *(const float4*)&W1L[kk * W1S + 4 * ct];  // contiguous across wave
            float zz[2] = {zv.x, zv.y};
            float ww[4] = {wv.x, wv.y, wv.z, wv.w};
            #pragma unroll
            for (int i = 0; i < 2; ++i)
                #pragma unroll
                for (int j = 0; j < 4; ++j) a_[i][j] += zz[i] * ww[j];
        }
        float h_[2][4];
        #pragma unroll
        for (int i = 0; i < 2; ++i)
            #pragma unroll
            for (int j = 0; j < 4; ++j) h_[i][j] = tanh_fast(a_[i][j]);
        #pragma unroll
        for (int i = 0; i < 2; ++i)
            *(float4*)&hRT[(2 * rt8 + i) * HSR + 4 * ct] =
                make_float4(h_[i][0], h_[i][1], h_[i][2], h_[i][3]);
        {
            float s0 = sL[4 * ct], s1 = sL[4 * ct + 1], s2 = sL[4 * ct + 2], s3 = sL[4 * ct + 3];
            #pragma unroll
            for (int i = 0; i < 2; ++i) {
                float t0 = s0 * (1.f - h_[i][0] * h_[i][0]);
                float t1 = s1 * (1.f - h_[i][1] * h_[i][1]);
                float t2 = s2 * (1.f - h_[i][2] * h_[i][2]);
                float t3 = s3 * (1.f - h_[i][3] * h_[i][3]);
                size_t rho = (size_t)(b0 + 2 * rt8 + i) * Hh + k;
                uint2 pk = make_uint2(f2bf_u(t0) | (f2bf_u(t1) << 16),
                                      f2bf_u(t2) | (f2bf_u(t3) << 16));
                *(uint2*)(tg + rho * HID + 4 * ct) = pk;   // coalesced 512 B/row/wave
            }
        }

        float unext = 0.f;
        if (tid < 256 && k < Hh - 1) {
            if (fast) {
                #pragma unroll
                for (int it = 0; it < 9; ++it) unext += v9[it];
            } else {
                for (int it = 0; it < nit - 1; ++it) unext += noise[(long)it * NS + nbase];
            }
            unext *= 0.001f;
        }

        __syncthreads();

        // ---- P2: x_next = x + 0.1*h@W2  (2 outputs/thread, same row) ----
        float xacc[2] = {0.f, 0.f};
        #pragma unroll 4
        for (int c8 = 0; c8 < HID / 8; ++c8) {
            float4 h0 = *(const float4*)&hRT[q16 * HSR + 8 * c8];
            float4 h1 = *(const float4*)&hRT[q16 * HSR + 8 * c8 + 4];
            float hf[8] = {h0.x, h0.y, h0.z, h0.w, h1.x, h1.y, h1.z, h1.w};
            #pragma unroll
            for (int i = 0; i < 2; ++i) {
                int d = cg + 32 * i;
                uint4 wv = *(const uint4*)&W2Tu[d * (W2S / 2) + 4 * c8];
                float wf[8];
                unpack8(wv, wf);
                #pragma unroll
                for (int jj = 0; jj < 8; ++jj) xacc[i] += hf[jj] * wf[jj];
            }
        }
        {
            const int bb = b0 + q16;
            #pragma unroll
            for (int i = 0; i < 2; ++i) {
                int d = cg + 32 * i;
                float xn = zT[d * 16 + q16] + 0.1f * xacc[i];
                out[O1 + bb * XT_PITCH + (k + 1) * NX + d] = xn;
                out[O2 + bb * PR_PITCH + k * NX + d] = xn;
                zT[d * 16 + q16] = xn;
            }
            if (tid < 256 && k < Hh - 1) zT[(NX + q16n) * 16 + r16n] = unext;
        }
    }
}

// =====================================================================
// K2: G[204800 x 80] = T[204800 x 256] @ W1^T, bf16 MFMA 16x16x32.
// A-fragments straight from global; only W1-bf16 in LDS. (unchanged)
// =====================================================================
__global__ __launch_bounds__(256) void ker_lin2(const float* __restrict__ W1,
                                                const ushort_t* __restrict__ Tg,
                                                float* __restrict__ out) {
    __shared__ __align__(16) ushort_t W1b[NXU * TLS];   // 42,240 B (only LDS)

    const int tid = threadIdx.x;
    const int r0 = blockIdx.x * 128;

    {
        const float4* W1f4 = (const float4*)W1;
        for (int i = tid; i < (NXU * HID) / 4; i += 256) {
            float4 w = W1f4[i];
            int p = i >> 6, c4 = i & 63;
            uint2 pk = make_uint2(f2bf_u(w.x) | (f2bf_u(w.y) << 16),
                                  f2bf_u(w.z) | (f2bf_u(w.w) << 16));
            *(uint2*)&W1b[p * TLS + 4 * c4] = pk;
        }
    }
    __syncthreads();

    const int wv = tid >> 6, lane = tid & 63;
    const int m = lane & 15, quad = lane >> 4;

    f32x4_t acc[2][5];
    #pragma unroll
    for (int i = 0; i < 2; ++i)
        #pragma unroll
        for (int j = 0; j < 5; ++j) acc[i][j] = (f32x4_t){0.f, 0.f, 0.f, 0.f};

    const ushort_t* Ta = Tg + (size_t)(r0 + wv * 32 + m) * HID;
    const ushort_t* Tb = Ta + (size_t)16 * HID;

    #pragma unroll
    for (int kc = 0; kc < 8; ++kc) {
        const int koff = kc * 32 + quad * 8;
        bf16x8_t a0 = *(const bf16x8_t*)&Ta[koff];
        bf16x8_t a1 = *(const bf16x8_t*)&Tb[koff];
        #pragma unroll
        for (int nt = 0; nt < 5; ++nt) {
            bf16x8_t bfr = *(const bf16x8_t*)&W1b[(nt * 16 + m) * TLS + koff];
            acc[0][nt] = __builtin_amdgcn_mfma_f32_16x16x32_bf16(a0, bfr, acc[0][nt], 0, 0, 0);
            acc[1][nt] = __builtin_amdgcn_mfma_f32_16x16x32_bf16(a1, bfr, acc[1][nt], 0, 0, 0);
        }
    }

    #pragma unroll
    for (int mt = 0; mt < 2; ++mt) {
        int rbase = r0 + wv * 32 + mt * 16 + quad * 4;
        #pragma unroll
        for (int r = 0; r < 4; ++r) {
            int rho = rbase + r;
            int b = (int)(((unsigned long long)rho * 1374389535ULL) >> 36);  // rho/50
            int kk = rho - b * 50;
            float* gxp = out + O3 + (size_t)b * PR_PITCH + kk * NX + m;
            #pragma unroll
            for (int nt = 0; nt < 4; ++nt)
                gxp[nt * 16] = 1.0f + acc[mt][nt][r];
            out[O4 + (size_t)b * U_PITCH + kk * NU + m] = acc[mt][4][r];
        }
    }
}

// =====================================================================
// Fallback: R2's proven fused kernel (used only if ws_size is too small)
// =====================================================================
__global__ __launch_bounds__(256) void ker_fused(const float* __restrict__ x0,
                                                 const float* __restrict__ W1,
                                                 const float* __restrict__ b1,
                                                 const float* __restrict__ W2,
                                                 const float* __restrict__ noise,
                                                 const int* __restrict__ nit_p,
                                                 float* __restrict__ out) {
    __shared__ __align__(16) float    W1L[NXU * W1S];
    __shared__ __align__(16) ushort_t W2T[NX * W2S];
    __shared__ __align__(16) float    hRT[16 * HS];
    __shared__ __align__(16) ushort_t tT[16 * TS];
    __shared__ __align__(16) float    zT[NXU * 16];
    __shared__ float b1L[HID];
    __shared__ float sL[HID];

    const int tid = threadIdx.x;
    const int b0 = blockIdx.x * 16;
    const int nit = nit_p[0];

    for (int i = tid; i < NXU * HID; i += 256)
        W1L[(i >> 8) * W1S + (i & 255)] = W1[i];
    for (int i = tid; i < HID * NX; i += 256) {
        int c = i >> 6, d = i & 63;
        W2T[d * W2S + c] = (ushort_t)f2bf_u(W2[i]);
    }
    b1L[tid] = b1[tid];
    for (int i = tid; i < 16 * NX; i += 256) {
        int r = i >> 6, d = i & 63;
        float v = x0[(b0 + r) * NX + d];
        zT[d * 16 + r] = v;
        out[O1 + (b0 + r) * XT_PITCH + d] = v;
    }
    const int r16 = tid >> 4, q16 = tid & 15;
    {
        long base = (long)(b0 + r16) * U_PITCH + q16;
        float s = 0.f;
        for (int it = 0; it < nit - 1; ++it) s += noise[(long)it * NS + base];
        zT[(NX + q16) * 16 + r16] = 0.001f * s;
        out[(b0 + r16) * NU + q16] = 0.001f * (s + noise[(long)(nit - 1) * NS + base]);
    }
    __syncthreads();
    {
        float s = 0.f;
        for (int d = 0; d < NX; ++d) s += bf2f(W2T[d * W2S + tid]);
        sL[tid] = 0.1f * s;
    }

    const int ct = tid & 63, rt = tid >> 6;
    uint* tTu = (uint*)tT;
    const uint* W2Tu = (const uint*)W2T;

    for (int k = 0; k < Hh; ++k) {
        __syncthreads();
        float v9[9];
        const bool fast = (k < Hh - 1) && (nit == 10);
        long nbase = (long)(b0 + r16) * U_PITCH + (k + 1) * NU + q16;
        if (fast) {
            #pragma unroll
            for (int it = 0; it < 9; ++it) v9[it] = noise[(long)it * NS + nbase];
        }
        float a_[4][4];
        {
            float bj[4];
            #pragma unroll
            for (int j = 0; j < 4; ++j) bj[j] = b1L[4 * ct + j];
            #pragma unroll
            for (int i = 0; i < 4; ++i)
                #pragma unroll
                for (int j = 0; j < 4; ++j) a_[i][j] = bj[j];
        }
        #pragma unroll 8
        for (int kk = 0; kk < NXU; ++kk) {
            float4 zv = *(const float4*)&zT[kk * 16 + 4 * rt];
            float4 wv = *(const float4*)&W1L[kk * W1S + 4 * ct];
            float zz[4] = {zv.x, zv.y, zv.z, zv.w};
            float ww[4] = {wv.x, wv.y, wv.z, wv.w};
            #pragma unroll
            for (int i = 0; i < 4; ++i)
                #pragma unroll
                for (int j = 0; j < 4; ++j) a_[i][j] += zz[i] * ww[j];
        }
        float h_[4][4];
        #pragma unroll
        for (int i = 0; i < 4; ++i)
            #pragma unroll
            for (int j = 0; j < 4; ++j) h_[i][j] = tanh_fast(a_[i][j]);
        #pragma unroll
        for (int i = 0; i < 4; ++i)
            *(float4*)&hRT[(4 * rt + i) * HS + 4 * ct] =
                make_float4(h_[i][0], h_[i][1], h_[i][2], h_[i][3]);
        {
            float s0 = sL[4 * ct], s1 = sL[4 * ct + 1], s2 = sL[4 * ct + 2], s3 = sL[4 * ct + 3];
            #pragma unroll
            for (int i = 0; i < 4; ++i) {
                float t0 = s0 * (1.f - h_[i][0] * h_[i][0]);
                float t1 = s1 * (1.f - h_[i][1] * h_[i][1]);
                float t2 = s2 * (1.f - h_[i][2] * h_[i][2]);
                float t3 = s3 * (1.f - h_[i][3] * h_[i][3]);
                tTu[(4 * rt + i) * (TS / 2) + 2 * ct]     = f2bf_u(t0) | (f2bf_u(t1) << 16);
                tTu[(4 * rt + i) * (TS / 2) + 2 * ct + 1] = f2bf_u(t2) | (f2bf_u(t3) << 16);
            }
        }
        float unext = 0.f;
        if (k < Hh - 1) {
            if (fast) {
                #pragma unroll
                for (int it = 0; it < 9; ++it) unext += v9[it];
            } else {
                for (int it = 0; it < nit - 1; ++it) unext += noise[(long)it * NS + nbase];
            }
            unext *= 0.001f;
        }
        __syncthreads();
        float xacc[4] = {0.f, 0.f, 0.f, 0.f};
        #pragma unroll 4
        for (int c8 = 0; c8 < HID / 8; ++c8) {
            float4 h0 = *(const float4*)&hRT[r16 * HS + 8 * c8];
            float4 h1 = *(const float4*)&hRT[r16 * HS + 8 * c8 + 4];
            float hf[8] = {h0.x, h0.y, h0.z, h0.w, h1.x, h1.y, h1.z, h1.w};
            #pragma unroll
            for (int i = 0; i < 4; ++i) {
                int d = q16 + 16 * i;
                uint4 wv = *(const uint4*)&W2Tu[d * (W2S / 2) + 4 * c8];
                float wf[8];
                unpack8(wv, wf);
                #pragma unroll
                for (int jj = 0; jj < 8; ++jj) xacc[i] += hf[jj] * wf[jj];
            }
        }
        {
            const int bb = b0 + r16;
            #pragma unroll
            for (int i = 0; i < 4; ++i) {
                int d = q16 + 16 * i;
                float xn = zT[d * 16 + r16] + 0.1f * xacc[i];
                out[O1 + bb * XT_PITCH + (k + 1) * NX + d] = xn;
                out[O2 + bb * PR_PITCH + k * NX + d] = xn;
                zT[d * 16 + r16] = xn;
            }
            if (k < Hh - 1) zT[(NX + q16) * 16 + r16] = unext;
        }
        {
            const uint* tTr = (const uint*)tT + r16 * (TS / 2);
            float g_[5] = {0.f, 0.f, 0.f, 0.f, 0.f};
            #pragma unroll 4
            for (int jc = 0; jc < HID / 8; ++jc) {
                uint4 tv = *(const uint4*)&tTr[4 * jc];
                float tf[8];
                unpack8(tv, tf);
                #pragma unroll
                for (int i = 0; i < 5; ++i) {
                    int p = q16 + 16 * i;
                    float4 w0 = *(const float4*)&W1L[p * W1S + 8 * jc];
                    float4 w1 = *(const float4*)&W1L[p * W1S + 8 * jc + 4];
                    g_[i] += tf[0] * w0.x + tf[1] * w0.y + tf[2] * w0.z + tf[3] * w0.w
                           + tf[4] * w1.x + tf[5] * w1.y + tf[6] * w1.z + tf[7] * w1.w;
                }
            }
            const int bb = b0 + r16;
            #pragma unroll
            for (int i = 0; i < 4; ++i)
                out[O3 + bb * PR_PITCH + k * NX + (q16 + 16 * i)] = 1.0f + g_[i];
            out[O4 + bb * U_PITCH + k * NU + q16] = g_[4];
        }
    }
}

extern "C" void kernel_launch(void* const* d_in, const int* in_sizes, int n_in,
                              void* d_out, int out_size, void* d_ws, size_t ws_size,
                              hipStream_t stream) {
    const float* x0    = (const float*)d_in[0];
    // d_in[1] = xref (unused)
    const float* W1    = (const float*)d_in[2];
    const float* b1    = (const float*)d_in[3];
    const float* W2    = (const float*)d_in[4];
    const float* noise = (const float*)d_in[5];
    const int*   nit   = (const int*)d_in[6];
    float* out = (float*)d_out;

    if (ws_size >= (size_t)T_BYTES) {
        ushort_t* tg = (ushort_t*)d_ws;
        ker_roll<<<Bsz / 16, 512, 0, stream>>>(x0, W1, b1, W2, noise, nit, out, tg);
        ker_lin2<<<(Bsz * Hh) / 128, 256, 0, stream>>>(W1, tg, out);
    } else {
        ker_fused<<<Bsz / 16, 256, 0, stream>>>(x0, W1, b1, W2, noise, nit, out);
    }
}